// Round 14
// baseline (446.950 us; speedup 1.0000x reference)
//
#include <hip/hip_runtime.h>
#include <stdint.h>

#define BB 1024
#define SS 512
#define HH 128
#define MM 4            // batch rows per block
#define BLK 256         // 4 waves, 1 per SIMD
#define NBLK (BB / MM)  // 256 blocks -> 1 per CU
#define HPS 136         // hpack row stride in f16 (272B rows -> 16B-aligned b128 reads)
#define RS 32           // h-trajectory ring slots (flush every 32 steps)
#define RStr 144        // ring row stride in f16 (R9 layout)

typedef float f32x4 __attribute__((ext_vector_type(4)));
typedef float f32x2 __attribute__((ext_vector_type(2)));
typedef _Float16 f16x8 __attribute__((ext_vector_type(8)));

#define LO_SCALE 2048.0f
#define LO_INV   (1.0f / 2048.0f)

__device__ __forceinline__ float sigf(float x) { return 1.0f / (1.0f + __expf(-x)); }
__device__ __forceinline__ float tanh_fast(float x) { return 2.0f / (1.0f + __expf(-2.0f * x)) - 1.0f; }

__global__ __launch_bounds__(BLK, 1) void pig_kernel(
    const float* __restrict__ x0, const float* __restrict__ v_seq,
    const float* __restrict__ W_ih, const float* __restrict__ W_hh,
    const float* __restrict__ b_ih, const float* __restrict__ b_hh,
    const float* __restrict__ W_out, const float* __restrict__ b_out,
    const float* __restrict__ W_r1, const float* __restrict__ b_r1,
    const float* __restrict__ W_r2, const float* __restrict__ b_r2,
    float* __restrict__ out)
{
    // hpack row r = 4m+p: p=0 -> h_hi[m], p=1 -> h_lo[m]*2048, p=2,3 -> zero
    __shared__ __align__(16) _Float16 hpack[2][16 * HPS];   // 8.7 KB
    __shared__ __align__(16) _Float16 ring[RS * MM * RStr]; // 36 KB: [slot][m][j] (hi only)
    __shared__ __align__(16) float    v_lds[SS * 8];        // 16 KB: [t][m*2+o]
    __shared__ __align__(16) float    xs[RS + 1][8];        // x_pred window (+carry at [0])
    __shared__ __align__(16) float    wpk[64][8];           // {W_r1[u][0..3], b_r1[u], W_r2[0][u], W_r2[1][u], 0}
    __shared__ float xc[2][8];                              // x_prev carry, flush-parity buffered

    const int tid  = threadIdx.x;
    const int wave = tid >> 6;        // 0..3
    const int lane = tid & 63;
    const int quad = lane >> 4;
    const int col  = lane & 15;
    const int row0 = blockIdx.x * MM;
    const int j0   = wave * 32 + col;        // lane's first hidden index
    const int j1   = j0 + 16;                // lane's second hidden index

    // ---- W_hh B-fragments (f16): wave w owns j-tiles {2w, 2w+1} for all 3 gates ----
    // 24 frags = 96 VGPRs; all indices compile-time (R12 lesson: runtime index -> spill)
    f16x8 whi[3][2][4];
#pragma unroll
    for (int nt = 0; nt < 3; ++nt)
#pragma unroll
        for (int jg = 0; jg < 2; ++jg) {
            const int g = nt * HH + wave * 32 + jg * 16 + col;
#pragma unroll
            for (int kk = 0; kk < 4; ++kk) {
                const float* p = W_hh + g * HH + kk * 32 + quad * 8;
                f16x8 fh;
#pragma unroll
                for (int i = 0; i < 8; ++i) fh[i] = (_Float16)p[i];
                whi[nt][jg][kk] = fh;
            }
        }

    // ---- gate-math per-lane constants: (m=quad, j0) and (m=quad, j1) ----
    float wih[2][6], bgc[2][4];
#pragma unroll
    for (int jg = 0; jg < 2; ++jg) {
        const int j = (jg == 0) ? j0 : j1;
        wih[jg][0] = W_ih[j*2];          wih[jg][1] = W_ih[j*2+1];
        wih[jg][2] = W_ih[(HH+j)*2];     wih[jg][3] = W_ih[(HH+j)*2+1];
        wih[jg][4] = W_ih[(2*HH+j)*2];   wih[jg][5] = W_ih[(2*HH+j)*2+1];
        bgc[jg][0] = b_ih[j]      + b_hh[j];
        bgc[jg][1] = b_ih[HH+j]   + b_hh[HH+j];
        bgc[jg][2] = b_ih[2*HH+j];
        bgc[jg][3] = b_hh[2*HH+j];
    }

    // ---- pass-A constants: g8 = tid>>3 in 0..31 -> (oA, mA, tt8 0..3); l8 lane-in-group ----
    const int g8  = tid >> 3;
    const int l8  = tid & 7;
    const int oA  = g8 & 1;
    const int mA  = (g8 >> 1) & 3;
    const int tt8 = g8 >> 3;            // 0..3
    float woA[16];
#pragma unroll
    for (int i = 0; i < 16; ++i) woA[i] = W_out[oA * HH + l8 * 16 + i];
    const float boA = b_out[oA];

    // ---- pass-B constants: thread = (tB 0..31, mB 0..3, qB 0..1) ----
    const int qB = tid & 1;
    const int mB = (tid >> 1) & 3;
    const int tB = tid >> 3;            // 0..31
    const float b2B = b_r2[qB];

    // ---- init ----
    for (int idx = tid; idx < 2 * 16 * HPS; idx += BLK) ((_Float16*)hpack)[idx] = (_Float16)0.0f;
    for (int idx = tid; idx < MM * SS * 2; idx += BLK) {
        const int m = idx >> 10, i = idx & 1023;          // i = t*2 + o
        v_lds[(i >> 1) * 8 + m * 2 + (i & 1)] = v_seq[(size_t)(row0 + m) * (SS * 2) + i];
    }
    if (tid < 64) {
        wpk[tid][0] = W_r1[tid*4];   wpk[tid][1] = W_r1[tid*4+1];
        wpk[tid][2] = W_r1[tid*4+2]; wpk[tid][3] = W_r1[tid*4+3];
        wpk[tid][4] = b_r1[tid];
        wpk[tid][5] = W_r2[tid];     wpk[tid][6] = W_r2[64 + tid];
        wpk[tid][7] = 0.0f;
    }
    if (tid < 8)
        xc[0][tid] = x0[(size_t)(row0 + (tid >> 1)) * 2 + (tid & 1)];
    __syncthreads();

    float hold0 = 0.0f, hold1 = 0.0f;   // h[quad][j0], h[quad][j1] in fp32
    for (int t = 0; t < SS; ++t) {
        const int cur = t & 1, nxt = cur ^ 1;

        // ---------- the bare recurrence: 24 MFMA in 6 independent chains ----------
        f32x4 a00 = {0,0,0,0}, a01 = {0,0,0,0};
        f32x4 a10 = {0,0,0,0}, a11 = {0,0,0,0};
        f32x4 a20 = {0,0,0,0}, a21 = {0,0,0,0};
#pragma unroll
        for (int kk = 0; kk < 4; ++kk) {
            f16x8 af = *(const f16x8*)&hpack[cur][col * HPS + kk * 32 + quad * 8];
            a00 = __builtin_amdgcn_mfma_f32_16x16x32_f16(af, whi[0][0][kk], a00, 0, 0, 0);
            a01 = __builtin_amdgcn_mfma_f32_16x16x32_f16(af, whi[0][1][kk], a01, 0, 0, 0);
            a10 = __builtin_amdgcn_mfma_f32_16x16x32_f16(af, whi[1][0][kk], a10, 0, 0, 0);
            a11 = __builtin_amdgcn_mfma_f32_16x16x32_f16(af, whi[1][1][kk], a11, 0, 0, 0);
            a20 = __builtin_amdgcn_mfma_f32_16x16x32_f16(af, whi[2][0][kk], a20, 0, 0, 0);
            a21 = __builtin_amdgcn_mfma_f32_16x16x32_f16(af, whi[2][1][kk], a21, 0, 0, 0);
        }
        // acc[0] = h_hi . W ; acc[1] = (h_lo*2048) . W  -> exact-h gh; m = quad
        const f32x2 vv2 = *(const f32x2*)&v_lds[t * 8 + quad * 2];
        const float v0 = vv2[0], v1 = vv2[1];

        const float gr0 = a00[0] + a00[1] * LO_INV;
        const float gz0 = a10[0] + a10[1] * LO_INV;
        const float gn0 = a20[0] + a20[1] * LO_INV;
        const float r0 = sigf(gr0 + v0*wih[0][0] + v1*wih[0][1] + bgc[0][0]);
        const float z0 = sigf(gz0 + v0*wih[0][2] + v1*wih[0][3] + bgc[0][1]);
        const float n0 = tanh_fast(v0*wih[0][4] + v1*wih[0][5] + bgc[0][2] + r0 * (gn0 + bgc[0][3]));
        hold0 = n0 + z0 * (hold0 - n0);

        const float gr1 = a01[0] + a01[1] * LO_INV;
        const float gz1 = a11[0] + a11[1] * LO_INV;
        const float gn1 = a21[0] + a21[1] * LO_INV;
        const float r1 = sigf(gr1 + v0*wih[1][0] + v1*wih[1][1] + bgc[1][0]);
        const float z1 = sigf(gz1 + v0*wih[1][2] + v1*wih[1][3] + bgc[1][1]);
        const float n1 = tanh_fast(v0*wih[1][4] + v1*wih[1][5] + bgc[1][2] + r1 * (gn1 + bgc[1][3]));
        hold1 = n1 + z1 * (hold1 - n1);

        const _Float16 hh0 = (_Float16)hold0;
        const _Float16 hh1 = (_Float16)hold1;
        hpack[nxt][(4*quad)     * HPS + j0] = hh0;
        hpack[nxt][(4*quad + 1) * HPS + j0] = (_Float16)((hold0 - (float)hh0) * LO_SCALE);
        hpack[nxt][(4*quad)     * HPS + j1] = hh1;
        hpack[nxt][(4*quad + 1) * HPS + j1] = (_Float16)((hold1 - (float)hh1) * LO_SCALE);
        const int rbase = ((t & (RS-1)) * 4 + quad) * RStr;
        ring[rbase + j0] = hh0;
        ring[rbase + j1] = hh1;

        __syncthreads();

        // ---------- batched epilogue every RS steps ----------
        if ((t & (RS - 1)) == (RS - 1)) {
            const int f  = t >> 5;
            const int t0 = t - (RS - 1);

            if (tid < 8) xs[0][tid] = xc[f & 1][tid];
#pragma unroll
            for (int p = 0; p < 8; ++p) {   // pass A: 32 groups x 8 passes cover 32tt x 4m x 2o
                const int tt = p * 4 + tt8;
                const f16x8 h0 = *(const f16x8*)&ring[(tt * 4 + mA) * RStr + l8 * 16];
                const f16x8 h1 = *(const f16x8*)&ring[(tt * 4 + mA) * RStr + l8 * 16 + 8];
                float acc = 0.0f;
#pragma unroll
                for (int i = 0; i < 8; ++i) {
                    acc += (float)h0[i] * woA[i];
                    acc += (float)h1[i] * woA[8 + i];
                }
                acc += __shfl_xor(acc, 1, 64);
                acc += __shfl_xor(acc, 2, 64);
                acc += __shfl_xor(acc, 4, 64);
                if (l8 == 0) xs[1 + tt][mA * 2 + oA] = acc + boA;
            }
            __syncthreads();

            {   // pass B: residual MLP + violations + stores; thread = (tB, mB, qB)
                const float xp0 = xs[tB][mB*2], xp1 = xs[tB][mB*2+1];
                const f32x2 vt2 = *(const f32x2*)&v_lds[(t0 + tB) * 8 + mB * 2];
                float rss0 = 0.0f, rss1 = 0.0f;
#pragma unroll
                for (int uu = 0; uu < 32; ++uu) {
                    const int u = qB * 32 + uu;
                    const f32x4 wA = *(const f32x4*)&wpk[u][0];
                    const f32x4 wB = *(const f32x4*)&wpk[u][4];
                    const float hu = fmaxf(wB[0] + wA[0]*xp0 + wA[1]*xp1 + wA[2]*vt2[0] + wA[3]*vt2[1], 0.0f);
                    rss0 += hu * wB[1];
                    rss1 += hu * wB[2];
                }
                rss0 += __shfl_xor(rss0, 1, 64);
                rss1 += __shfl_xor(rss1, 1, 64);
                {
                    const int o = qB;
                    const float xpred = xs[tB + 1][mB*2 + o];
                    const float xpv   = xs[tB][mB*2 + o];
                    const float vv    = v_lds[(t0 + tB) * 8 + mB*2 + o];
                    const float resid = (o ? rss1 : rss0) + b2B;
                    const float viol  = xpred - (xpv + vv + resid);
                    const size_t base = (size_t)(row0 + mB) * (SS * 2) + (t0 + tB) * 2 + o;
                    out[base] = xpred;
                    out[(size_t)BB * SS * 2 + base] = viol;
                }
                if (tid < 8) xc[(f + 1) & 1][tid] = xs[RS][tid];
            }
            __syncthreads();
        }
    }
}

extern "C" void kernel_launch(void* const* d_in, const int* in_sizes, int n_in,
                              void* d_out, int out_size, void* d_ws, size_t ws_size,
                              hipStream_t stream) {
    pig_kernel<<<dim3(NBLK), dim3(BLK), 0, stream>>>(
        (const float*)d_in[0],  (const float*)d_in[1],  (const float*)d_in[2],
        (const float*)d_in[3],  (const float*)d_in[4],  (const float*)d_in[5],
        (const float*)d_in[6],  (const float*)d_in[7],  (const float*)d_in[8],
        (const float*)d_in[9],  (const float*)d_in[10], (const float*)d_in[11],
        (float*)d_out);
}